// Round 16
// baseline (1343.441 us; speedup 1.0000x reference)
//
#include <hip/hip_runtime.h>
#include <hip/hip_bf16.h>

#define DEV static __device__ __forceinline__

typedef __attribute__((ext_vector_type(8))) short bf16x8;   // 8 bf16 = 4 VGPR (MFMA A/B frag)
typedef __attribute__((ext_vector_type(4))) float f32x4;    // MFMA C/D frag
typedef __attribute__((ext_vector_type(4))) unsigned short u16x4;
typedef __attribute__((ext_vector_type(4))) unsigned int u32x4;

constexpr int Lc = 6, Dc = 1024, Sc = 2048, Fc = 4096, Hc = 16, Bc = 2;
constexpr int Mc = Bc * Sc;   // 4096 activation rows
constexpr int QKVN = 3 * Dc;  // fused QKV width
constexpr float QSCALE = 0.18033688011112042f;  // log2(e)/8, folded into Wq/bq

DEV float bf2f(unsigned short u) {
  unsigned int x = ((unsigned int)u) << 16; float f;
  __builtin_memcpy(&f, &x, 4); return f;
}
DEV unsigned short f2bf(float f) {   // RNE
  unsigned int x; __builtin_memcpy(&x, &f, 4);
  x += 0x7fffu + ((x >> 16) & 1u);
  return (unsigned short)(x >> 16);
}
DEV unsigned int cvt_pk_bf16(float lo, float hi) {  // (bf16(hi)<<16)|bf16(lo), RNE
  unsigned int r;
  asm("v_cvt_pk_bf16_f32 %0, %1, %2" : "=v"(r) : "v"(lo), "v"(hi));
  return r;
}

typedef __attribute__((address_space(1))) unsigned int* gas_t;
typedef __attribute__((address_space(3))) unsigned int* las_t;
DEV void gload16(const void* g, void* l) {
  __builtin_amdgcn_global_load_lds((gas_t)g, (las_t)l, 16, 0, 0);
}

DEV int vperm(int k) {   // within 64; preserves k&3
  return ((k >> 5) << 5) + (((k >> 2) & 3) << 3) + (((k >> 4) & 1) << 2) + (k & 3);
}

// ------------------------------------------------- fused ALL-layer weight prep
// 64(n) x 256(k) per block, 4 sub-tiles of 64x64. Loads f32x4 (16B/lane),
// stores u16x4 (8B/lane). tile[64][65]: both phases ~2-way bank alias (free).
DEV void tr64v(const float* __restrict__ W, unsigned short* __restrict__ Wt,
               int Kd, int Nd, float scale, int bx, int by, int tid,
               float (*tile)[65])
{
  const int n0 = bx * 64;
#pragma unroll
  for (int s = 0; s < 4; ++s) {
    const int k0 = by * 256 + s * 64;
#pragma unroll
    for (int it = 0; it < 4; ++it) {
      int idx = it * 256 + tid;
      int k = idx >> 4, c0 = (idx & 15) * 4;
      *(f32x4*)&tile[k][c0] = *(const f32x4*)&W[(size_t)(k0 + k) * Nd + n0 + c0];
    }
    __syncthreads();
#pragma unroll
    for (int it = 0; it < 4; ++it) {
      int idx = it * 256 + tid;
      int n = idx >> 4, kc = (idx & 15) * 4;
      u16x4 o;
#pragma unroll
      for (int j = 0; j < 4; ++j) o[j] = f2bf(tile[kc + j][n] * scale);
      *(u16x4*)&Wt[(size_t)(n0 + n) * Kd + k0 + kc] = o;
    }
    __syncthreads();
  }
}

// Per layer 780 blocks: [0,256) 4x DxD (64 ea) | [256,512) W1 |
// [512,768) W2 | [768,780) bias pack.
__global__ __launch_bounds__(256) void prep_weights(
    const float* __restrict__ Wq, const float* __restrict__ Wk,
    const float* __restrict__ Wv, const float* __restrict__ Wo,
    const float* __restrict__ W1, const float* __restrict__ W2,
    const float* __restrict__ bq, const float* __restrict__ bk,
    const float* __restrict__ bv,
    unsigned short* __restrict__ Wqkvt, unsigned short* __restrict__ Wot,
    unsigned short* __restrict__ W1t, unsigned short* __restrict__ W2t,
    float* __restrict__ bqkv)
{
  __shared__ float tile[64][65];
  const int l = blockIdx.x / 780;
  const int id = blockIdx.x % 780;
  const int t = threadIdx.x;
  const size_t owD = (size_t)l * Dc * Dc, owF = (size_t)l * Dc * Fc;
  unsigned short* Wqkvt_l = Wqkvt + (size_t)l * 3 * Dc * Dc;
  unsigned short* Wot_l = Wot + (size_t)l * Dc * Dc;
  unsigned short* W1t_l = W1t + owF;
  unsigned short* W2t_l = W2t + owF;
  if (id < 256) {            // 4 DxD: bx in [0,16), by in [0,4)
    int which = id >> 6, lo = id & 63;
    int bx = lo & 15, by = lo >> 4;
    if (which == 0)      tr64v(Wq + owD, Wqkvt_l, Dc, Dc, QSCALE, bx, by, t, tile);
    else if (which == 1) tr64v(Wk + owD, Wqkvt_l + (size_t)Dc * Dc, Dc, Dc, 1.0f, bx, by, t, tile);
    else if (which == 2) tr64v(Wv + owD, Wqkvt_l + (size_t)2 * Dc * Dc, Dc, Dc, 1.0f, bx, by, t, tile);
    else                 tr64v(Wo + owD, Wot_l, Dc, Dc, 1.0f, bx, by, t, tile);
  } else if (id < 512) {     // W1 [1024 x 4096]: bx in [0,64), by in [0,4)
    int lo = id - 256;
    tr64v(W1 + owF, W1t_l, Dc, Fc, 1.0f, lo & 63, lo >> 6, t, tile);
  } else if (id < 768) {     // W2 [4096 x 1024]: bx in [0,16), by in [0,16)
    int lo = id - 512;
    tr64v(W2 + owF, W2t_l, Fc, Dc, 1.0f, lo & 15, lo >> 4, t, tile);
  } else {                   // bias pack
    int i = (id - 768) * 256 + t;
    const int ob = l * Dc;
    bqkv[l * QKVN + i] =
        (i < Dc) ? bq[ob + i] * QSCALE
                 : (i < 2 * Dc ? bk[ob + i - Dc] : bv[ob + i - 2 * Dc]);
  }
}

// ---------------------------------------------------------------- embed + PE
__global__ __launch_bounds__(256) void embed_kernel(
    const int* __restrict__ tokens, const float* __restrict__ emb,
    unsigned short* __restrict__ xb)
{
  const int bs = blockIdx.x;            // b*S + s
  const int s = bs & (Sc - 1);
  const int tok = tokens[bs];
  const int d0 = threadIdx.x * 4;
  f32x4 e4 = *(const f32x4*)(emb + (size_t)tok * Dc + d0);
  u16x4 vb;
#pragma unroll
  for (int j = 0; j < 4; ++j) {
    int d = d0 + j;
    float e = e4[j] * 32.0f;                             // sqrt(D)=32
    float fr = expf((float)(d & ~1) * (-9.210340371976184f / 1024.0f));
    float arg = (float)s * fr;
    float pe = (d & 1) ? cosf(arg) : sinf(arg);
    vb[j] = f2bf(e + pe);
  }
  *(u16x4*)(xb + (size_t)bs * Dc + d0) = vb;
}

// ------------------------------------------------------- 256x256 8-phase core
DEV void gemm256_core(const unsigned short* __restrict__ A,
                      const unsigned short* __restrict__ Bt,
                      unsigned short (*As)[256 * 64], unsigned short (*Bs)[256 * 64],
                      f32x4 (*acc)[4], int mTile, int nTile,
                      int Kstride, int k0, int nT, int t)
{
  const int lane = t & 63;
  const int g = lane >> 4, li = lane & 15;
  const int w = t >> 6;
  const int wm = w >> 2, wn = w & 3;
  const int trow = t >> 3, tslot = t & 7;
  const int asl = tslot ^ (trow & 7);
  int aoff[4];
#pragma unroll
  for (int q = 0; q < 4; ++q) {
    int R = (trow < 32) ? (q * 32 + trow) : (96 + q * 32 + trow);
    aoff[q] = (mTile + R) * Kstride + k0 + asl * 8;
  }
  int boff[4], bld[4];
#pragma unroll
  for (int k2 = 0; k2 < 4; ++k2) {
    int idx = k2 * 512 + t;
    int br = idx >> 3;
    int bs = (idx & 7) ^ (br & 7);
    boff[k2] = (nTile + br) * Kstride + k0 + bs * 8;
    bld[k2] = idx * 8;
  }

  auto stB = [&](int nb, int kt, int ph) {
    gload16(Bt + boff[ph * 2 + 0] + kt, &Bs[nb][bld[ph * 2 + 0]]);
    gload16(Bt + boff[ph * 2 + 1] + kt, &Bs[nb][bld[ph * 2 + 1]]);
  };
  auto stA = [&](int nb, int kt, int ph) {
    gload16(A + aoff[ph * 2 + 0] + kt, &As[nb][(ph * 2 + 0) * 4096 + t * 8]);
    gload16(A + aoff[ph * 2 + 1] + kt, &As[nb][(ph * 2 + 1) * 4096 + t * 8]);
  };

  // prologue: stage tile 0 fully
  stB(0, 0, 0); stB(0, 0, 1); stA(0, 0, 0); stA(0, 0, 1);
  asm volatile("s_waitcnt vmcnt(0)" ::: "memory");
  __builtin_amdgcn_s_barrier();

  int cur = 0;
  for (int tt = 0; tt < nT; ++tt) {
    const char* Ac = (const char*)As[cur];
    const char* Bc = (const char*)Bs[cur];
    const int nb = cur ^ 1;
    const int ktn = (tt + 1) << 6;
    const bool more = tt + 1 < nT;

    bf16x8 bfr[4][2];
#pragma unroll
    for (int ni = 0; ni < 4; ++ni) {
      const int rn = wn * 64 + ni * 16 + li;
#pragma unroll
      for (int ks = 0; ks < 2; ++ks) {
        const int kb = ks * 64 + (g << 4);
        bfr[ni][ks] = *(const bf16x8*)(Bc + rn * 128 + (kb ^ ((rn & 7) << 4)));
      }
    }

#pragma unroll
    for (int ph = 0; ph < 4; ++ph) {
      bf16x8 afr[2][2];
#pragma unroll
      for (int mi2 = 0; mi2 < 2; ++mi2) {
        const int rr = wm * 32 + mi2 * 16 + li;
#pragma unroll
        for (int ks = 0; ks < 2; ++ks) {
          const int kb = ks * 64 + (g << 4);
          afr[mi2][ks] = *(const bf16x8*)(Ac + ph * 8192 + rr * 128 + (kb ^ ((rr & 7) << 4)));
        }
      }
      if (more) {
        if (ph == 0)      stB(nb, ktn, 0);
        else if (ph == 1) stB(nb, ktn, 1);
        else if (ph == 2) stA(nb, ktn, 0);
        else              stA(nb, ktn, 1);
      }
      __builtin_amdgcn_s_barrier();
      __builtin_amdgcn_s_setprio(1);
#pragma unroll
      for (int mi2 = 0; mi2 < 2; ++mi2)
#pragma unroll
        for (int ni = 0; ni < 4; ++ni)
#pragma unroll
          for (int ks = 0; ks < 2; ++ks)
            acc[ph * 2 + mi2][ni] = __builtin_amdgcn_mfma_f32_16x16x32_bf16(
                afr[mi2][ks], bfr[ni][ks], acc[ph * 2 + mi2][ni], 0, 0, 0);
      __builtin_amdgcn_s_setprio(0);
      if (ph == 0)      asm volatile("s_waitcnt vmcnt(4)" ::: "memory");
      else if (ph == 1) asm volatile("s_waitcnt vmcnt(5)" ::: "memory");
      else if (ph == 2) asm volatile("s_waitcnt vmcnt(6)" ::: "memory");
      else              asm volatile("s_waitcnt vmcnt(3)" ::: "memory");
      __builtin_amdgcn_s_barrier();
    }
    cur ^= 1;
  }
}

// full-K 256^2 GEMM + bias/relu epilogue; for QKV, V-columns (c>=2048) are
// written transposed+vperm'd directly to Vt (replacing transpose_v).
__global__ __launch_bounds__(512) void gemm256(
    const unsigned short* __restrict__ A, const unsigned short* __restrict__ Bt,
    const float* __restrict__ bias, unsigned short* __restrict__ outB,
    unsigned short* __restrict__ Vt, int gx, int Ndim, int Kdim, int relu)
{
  __shared__ alignas(16) unsigned short As[2][256 * 64];
  __shared__ alignas(16) unsigned short Bs[2][256 * 64];
  const int t = threadIdx.x;
  const int lane = t & 63, w = t >> 6;
  const int wm = w >> 2, wn = w & 3;
  const int g = lane >> 4, li = lane & 15;
  const int nwg = gridDim.x, flat = blockIdx.x;
  const int swz = (flat & 7) * (nwg >> 3) + (flat >> 3);
  const int mTile = (swz / gx) * 256;
  const int nTile = (swz % gx) * 256;

  f32x4 acc[8][4] = {};
  gemm256_core(A, Bt, As, Bs, acc, mTile, nTile, Kdim, 0, Kdim >> 6, t);

  const bool vblk = (Vt != nullptr) && (nTile >= 2 * Dc);
#pragma unroll
  for (int mi = 0; mi < 8; ++mi) {
#pragma unroll
    for (int ni = 0; ni < 4; ++ni) {
      const int c = nTile + wn * 64 + ni * 16 + li;
      const float bvv = bias[c];
      if (!vblk) {
#pragma unroll
        for (int j = 0; j < 4; ++j) {
          const int r = mTile + wm * 128 + mi * 16 + g * 4 + j;
          float v = acc[mi][ni][j] + bvv;
          if (relu) v = fmaxf(v, 0.0f);
          outB[(size_t)r * Ndim + c] = f2bf(v);
        }
      } else {
        const int r0 = mTile + wm * 128 + mi * 16 + g * 4;   // %4 == 0
        const int b = r0 >> 11, s0 = r0 & 2047;
        const int sp = (s0 & ~63) + vperm(s0 & 63);          // contiguous for j
        u16x4 ov;
#pragma unroll
        for (int j = 0; j < 4; ++j) ov[j] = f2bf(acc[mi][ni][j] + bvv);
        *(u16x4*)(Vt + ((size_t)(b * Dc + (c - 2 * Dc))) * Sc + sp) = ov;
      }
    }
  }
}

// split-K 256^2 GEMM: writes bf16 partials part[z][M][N]. grid=gx*gy*SPLIT.
template<int SPLIT>
__global__ __launch_bounds__(512) void gemm256_sk(
    const unsigned short* __restrict__ A, const unsigned short* __restrict__ Bt,
    unsigned short* __restrict__ part, int gx, int gy, int Ndim, int Ktot)
{
  __shared__ alignas(16) unsigned short As[2][256 * 64];
  __shared__ alignas(16) unsigned short Bs[2][256 * 64];
  const int t = threadIdx.x;
  const int lane = t & 63, w = t >> 6;
  const int wm = w >> 2, wn = w & 3;
  const int g = lane >> 4, li = lane & 15;
  const int nwg = gridDim.x, flat = blockIdx.x;
  const int swz = (flat & 7) * (nwg >> 3) + (flat >> 3);
  const int nTile = (swz % gx) * 256;
  const int mTile = ((swz / gx) % gy) * 256;
  const int z = swz / (gx * gy);
  const int Kseg = Ktot / SPLIT;

  f32x4 acc[8][4] = {};
  gemm256_core(A, Bt, As, Bs, acc, mTile, nTile, Ktot, z * Kseg, Kseg >> 6, t);

  unsigned short* po = part + (size_t)z * Mc * Ndim;
#pragma unroll
  for (int mi = 0; mi < 8; ++mi)
#pragma unroll
    for (int ni = 0; ni < 4; ++ni) {
      const int c = nTile + wn * 64 + ni * 16 + li;
#pragma unroll
      for (int j = 0; j < 4; ++j) {
        const int r = mTile + wm * 128 + mi * 16 + g * 4 + j;
        po[(size_t)r * Ndim + c] = f2bf(acc[mi][ni][j]);
      }
    }
}

// ---------------------------------------------------------------- attention
// QBLK=128, 512 blocks (XCD-swizzled), 4 waves split 2x2 over (q,k):
// wave (wq,wk) owns q rows [wq*64,+64) x k range [wk*1024,+1024).
// Each K/V LDS fragment feeds 4 MFMAs (2x the q-split version) -> per-wave
// LDS traffic halves; 16 barriers instead of 32. Softmax (no-max) is additive
// in k, so the two k-halves merge via one 32KB LDS reduction in the epilogue
// (overlaying the dead K buffers). LDS 80KB -> 2 blocks/CU.
__global__ __launch_bounds__(256, 2) void attn128(
    const unsigned short* __restrict__ QKV, const unsigned short* __restrict__ Vt,
    unsigned short* __restrict__ O)
{
  __shared__ alignas(16) char smem[80 * 1024];
  unsigned short* Qs  = (unsigned short*)smem;                 // 16 KB
  unsigned short* KsB = (unsigned short*)(smem + 16 * 1024);   // 32 KB: [dbuf*2+col]
  unsigned short* VsB = (unsigned short*)(smem + 48 * 1024);   // 32 KB

  const int t = threadIdx.x;
  const int lane = t & 63, w = t >> 6;
  const int wq = w >> 1, wk = w & 1;
  const int g = lane >> 4, li = lane & 15;
  const int flat = blockIdx.x;
  const int idx = ((flat & 7) << 6) | (flat >> 3);     // 512 blocks, 64/XCD
  const int qb = idx & 15, bh = idx >> 4;              // 16 q-blocks per head
  const int b = bh >> 4, h = bh & 15;

  const size_t qbase  = ((size_t)(b * Sc + qb * 128)) * QKVN + h * 64;
  const size_t kbase0 = ((size_t)b * Sc) * QKVN + Dc + h * 64;
  const size_t vbase0 = ((size_t)(b * Dc + h * 64)) * Sc;

#pragma unroll
  for (int i = 0; i < 4; ++i) {
    int idx2 = i * 256 + t, row = idx2 >> 3, sl = (idx2 & 7) ^ (row & 7);
    gload16(QKV + qbase + (size_t)row * QKVN + sl * 8, &Qs[idx2 * 8]);
  }
  const unsigned short* kg[2];
  const unsigned short* vg[2];
  int loff[2];
#pragma unroll
  for (int i = 0; i < 2; ++i) {
    int idx2 = i * 256 + t, row = idx2 >> 3, sl = (idx2 & 7) ^ (row & 7);
    kg[i] = QKV + kbase0 + (size_t)row * QKVN + sl * 8;
    vg[i] = Vt + vbase0 + (size_t)row * Sc + sl * 8;
    loff[i] = idx2 * 8;
  }
  const size_t KC = (size_t)1024 * QKVN;   // col-1 K offset (k += 1024)

  // prologue: stage chunk 0 of both k-columns into dbuf 0
#pragma unroll
  for (int c = 0; c < 2; ++c) {
    gload16(kg[0] + c * KC, &KsB[(0 * 2 + c) * 4096 + loff[0]]);
    gload16(kg[1] + c * KC, &KsB[(0 * 2 + c) * 4096 + loff[1]]);
    gload16(vg[0] + c * 1024, &VsB[(0 * 2 + c) * 4096 + loff[0]]);
    gload16(vg[1] + c * 1024, &VsB[(0 * 2 + c) * 4096 + loff[1]]);
  }
  kg[0] += 64 * QKVN; kg[1] += 64 * QKVN;
  vg[0] += 64;        vg[1] += 64;
  __syncthreads();   // Q + chunk0 (both cols) resident

  bf16x8 qf[4][2];
#pragma unroll
  for (int qi = 0; qi < 4; ++qi) {
    const int rq = wq * 64 + qi * 16 + li;
#pragma unroll
    for (int ks = 0; ks < 2; ++ks) {
      const int kb = ks * 64 + (g << 4);
      qf[qi][ks] = *(const bf16x8*)((const char*)Qs + rq * 128 + (kb ^ ((rq & 7) << 4)));
    }
  }
  bf16x8 ones;
#pragma unroll
  for (int e = 0; e < 8; ++e) ones[e] = (short)0x3F80;  // bf16 1.0

  f32x4 acc_o[4][4] = {};
  f32x4 acc_l[4] = {};

  for (int tt = 0; tt < 16; ++tt) {
    const int cur = tt & 1;
    if (tt + 1 < 16) {
      const int nb = cur ^ 1;
#pragma unroll
      for (int c = 0; c < 2; ++c) {
        gload16(kg[0] + c * KC, &KsB[(nb * 2 + c) * 4096 + loff[0]]);
        gload16(kg[1] + c * KC, &KsB[(nb * 2 + c) * 4096 + loff[1]]);
        gload16(vg[0] + c * 1024, &VsB[(nb * 2 + c) * 4096 + loff[0]]);
        gload16(vg[1] + c * 1024, &VsB[(nb * 2 + c) * 4096 + loff[1]]);
      }
      kg[0] += 64 * QKVN; kg[1] += 64 * QKVN;
      vg[0] += 64;        vg[1] += 64;
    }
    const char* Kc = (const char*)(KsB + (cur * 2 + wk) * 4096);
    const char* Vc = (const char*)(VsB + (cur * 2 + wk) * 4096);

    // swapped QK^T: each K fragment feeds all 4 q-subtiles
    f32x4 accs[4][4] = {};
#pragma unroll
    for (int ks = 0; ks < 2; ++ks) {
      const int kb = ks * 64 + (g << 4);
#pragma unroll
      for (int ni = 0; ni < 4; ++ni) {
        const int rk = ni * 16 + li;
        bf16x8 ak = *(const bf16x8*)(Kc + rk * 128 + (kb ^ ((rk & 7) << 4)));
#pragma unroll
        for (int qi = 0; qi < 4; ++qi)
          accs[qi][ni] = __builtin_amdgcn_mfma_f32_16x16x32_bf16(
              ak, qf[qi][ks], accs[qi][ni], 0, 0, 0);
      }
    }

    unsigned int pk[4][4][2];
#pragma unroll
    for (int qi = 0; qi < 4; ++qi)
#pragma unroll
      for (int ni = 0; ni < 4; ++ni) {
        float p0 = exp2f(accs[qi][ni][0]);
        float p1 = exp2f(accs[qi][ni][1]);
        float p2 = exp2f(accs[qi][ni][2]);
        float p3 = exp2f(accs[qi][ni][3]);
        pk[qi][ni][0] = cvt_pk_bf16(p0, p1);
        pk[qi][ni][1] = cvt_pk_bf16(p2, p3);
      }

#pragma unroll
    for (int ks = 0; ks < 2; ++ks) {
      bf16x8 ap[4];
#pragma unroll
      for (int qi = 0; qi < 4; ++qi) {
        u32x4 av = {pk[qi][2 * ks][0], pk[qi][2 * ks][1],
                    pk[qi][2 * ks + 1][0], pk[qi][2 * ks + 1][1]};
        ap[qi] = __builtin_bit_cast(bf16x8, av);
        acc_l[qi] = __builtin_amdgcn_mfma_f32_16x16x32_bf16(ap[qi], ones, acc_l[qi], 0, 0, 0);
      }
      const int kb = ks * 64 + (g << 4);
#pragma unroll
      for (int ni = 0; ni < 4; ++ni) {
        const int rd = ni * 16 + li;
        bf16x8 bv = *(const bf16x8*)(Vc + rd * 128 + (kb ^ ((rd & 7) << 4)));
#pragma unroll
        for (int qi = 0; qi < 4; ++qi)
          acc_o[qi][ni] = __builtin_amdgcn_mfma_f32_16x16x32_bf16(
              ap[qi], bv, acc_o[qi][ni], 0, 0, 0);
      }
    }

    __syncthreads();
  }

  // cross-wk reduction: wk=1 dumps partials into dead K/V LDS; wk=0 merges.
  float* red  = (float*)(smem + 16 * 1024);   // 32 KB: acc_o partials
  float* red2 = (float*)(smem + 48 * 1024);   // 512 B: acc_l partials
  if (wk == 1) {
#pragma unroll
    for (int qi = 0; qi < 4; ++qi) {
#pragma unroll
      for (int ni = 0; ni < 4; ++ni)
#pragma unroll
        for (int j = 0; j < 4; ++j)
          red[((((wq * 4 + qi) * 4 + ni) * 16) + g * 4 + j) * 16 + li] = acc_o[qi][ni][j];
      if (li == 0)
#pragma unroll
        for (int j = 0; j < 4; ++j)
          red2[(wq * 4 + qi) * 16 + g * 4 + j] = acc_l[qi][j];
    }
  }
  __syncthreads();
  if (wk == 0) {
    const size_t obase = ((size_t)(b * Sc + qb * 128)) * Dc + h * 64;
#pragma unroll
    for (int qi = 0; qi < 4; ++qi) {
      float denom[4];
#pragma unroll
      for (int j = 0; j < 4; ++j)
        denom[j] = 1.0f / (acc_l[qi][j] + red2[(wq * 4 + qi) * 16 + g * 4 + j]);
#pragma unroll
      for (int ni = 0; ni < 4; ++ni)
#pragma unroll
        for (int j = 0; j < 4; ++j) {
          float v = acc_o[qi][ni][j] +
                    red[((((wq * 4 + qi) * 4 + ni) * 16) + g * 4 + j) * 16 + li];
          int q = wq * 64 + qi * 16 + g * 4 + j;
          O[obase + (size_t)q * Dc + ni * 16 + li] = f2bf(v * denom[j]);
        }
    }
  }
}

// ------------------------- split-K (bf16) reduce + layernorm, bf16 residual
template<int SPLIT>
__global__ __launch_bounds__(256) void reduce_ln(
    const unsigned short* __restrict__ part, const float* __restrict__ bias,
    const unsigned short* __restrict__ resb, const float* __restrict__ g,
    const float* __restrict__ be, float* __restrict__ fout,
    unsigned short* __restrict__ xb_out)
{
  const int row = blockIdx.x, t = threadIdx.x;
  const size_t off = (size_t)row * Dc + t * 4;
  u16x4 rv = *(const u16x4*)(resb + off);
  f32x4 v;
#pragma unroll
  for (int j = 0; j < 4; ++j) v[j] = bf2f(rv[j]);
  v += *(const f32x4*)(bias + t * 4);
#pragma unroll
  for (int s = 0; s < SPLIT; ++s) {
    u16x4 pv = *(const u16x4*)(part + (size_t)s * Mc * Dc + off);
#pragma unroll
    for (int j = 0; j < 4; ++j) v[j] += bf2f(pv[j]);
  }

  float sm = v[0] + v[1] + v[2] + v[3];
  float q = v[0]*v[0] + v[1]*v[1] + v[2]*v[2] + v[3]*v[3];
#pragma unroll
  for (int o = 32; o; o >>= 1) {
    sm += __shfl_down(sm, o);
    q += __shfl_down(q, o);
  }
  __shared__ float rs_[4], rq_[4];
  const int lane = t & 63, w = t >> 6;
  if (lane == 0) { rs_[w] = sm; rq_[w] = q; }
  __syncthreads();
  sm = rs_[0] + rs_[1] + rs_[2] + rs_[3];
  q = rq_[0] + rq_[1] + rq_[2] + rq_[3];
  const float mu = sm * (1.0f / 1024.0f);
  const float var = q * (1.0f / 1024.0f) - mu * mu;
  const float rstd = rsqrtf(var + 1e-5f);
  f32x4 vg = *(const f32x4*)(g + t * 4);
  f32x4 vb = *(const f32x4*)(be + t * 4);
  f32x4 o; u16x4 ob;
#pragma unroll
  for (int j = 0; j < 4; ++j) {
    float val = (v[j] - mu) * rstd * vg[j] + vb[j];
    o[j] = val; ob[j] = f2bf(val);
  }
  if (fout) *(f32x4*)(fout + off) = o;
  *(u16x4*)(xb_out + off) = ob;
}

// ---------------------------------------------------------------- launch
extern "C" void kernel_launch(void* const* d_in, const int* in_sizes, int n_in,
                              void* d_out, int out_size, void* d_ws, size_t ws_size,
                              hipStream_t stream)
{
  (void)in_sizes; (void)n_in; (void)out_size; (void)ws_size;
  const int*   tokens = (const int*)d_in[0];
  const float* emb = (const float*)d_in[1];
  const float* Wq = (const float*)d_in[2];
  const float* bq = (const float*)d_in[3];
  const float* Wk = (const float*)d_in[4];
  const float* bk = (const float*)d_in[5];
  const float* Wv = (const float*)d_in[6];
  const float* bv = (const float*)d_in[7];
  const float* Wo = (const float*)d_in[8];
  const float* bo = (const float*)d_in[9];
  const float* W1 = (const float*)d_in[10];
  const float* b1 = (const float*)d_in[11];
  const float* W2 = (const float*)d_in[12];
  const float* b2 = (const float*)d_in[13];
  const float* g1 = (const float*)d_in[14];
  const float* be1 = (const float*)d_in[15];
  const float* g2 = (const float*)d_in[16];
  const float* be2 = (const float*)d_in[17];

  char* p = (char*)d_ws;
  auto take = [&](size_t bytes) { char* q = p; p += bytes; return q; };
  // ALL-layer transposed weights (prepped once, before the layer loop)
  unsigned short* Wqkvt = (unsigned short*)take((size_t)Lc * 3 * Dc * Dc * 2); // 36 MB
  unsigned short* Wot = (unsigned short*)take((size_t)Lc * Dc * Dc * 2);       // 12 MB
  unsigned short* W1t = (unsigned short*)take((size_t)Lc * Dc * Fc * 2);       // 48 MB
  unsigned short* W2t = (unsigned short*)take((size_t)Lc * Fc * Dc * 2);       // 48 MB
  float*          bqkv = (float*)take((size_t)Lc * QKVN * 4);
  unsigned short* xb  = (unsigned short*)take((size_t)Mc * Dc * 2);
  unsigned short* QKVb = (unsigned short*)take((size_t)Mc * QKVN * 2);
  unsigned short* Vtb = (unsigned short*)take((size_t)Bc * Dc * Sc * 2);
  unsigned short* Ob  = (unsigned short*)take((size_t)Mc * Dc * 2);
  unsigned short* ff1 = (unsigned short*)take((size_t)Mc * Fc * 2);
  // split-K bf16 partials (4 x 8 MB) overlay QKVb+Vtb (dead after attn)
  unsigned short* part = QKVb;

  dim3 blk(256);
  prep_weights<<<dim3(Lc * 780), blk, 0, stream>>>(
      Wq, Wk, Wv, Wo, W1, W2, bq, bk, bv, Wqkvt, Wot, W1t, W2t, bqkv);
  embed_kernel<<<dim3(Mc), blk, 0, stream>>>(tokens, emb, xb);

  for (int l = 0; l < Lc; ++l) {
    const int ob = l * Dc;
    const unsigned short* Wqkvt_l = Wqkvt + (size_t)l * 3 * Dc * Dc;
    const unsigned short* Wot_l = Wot + (size_t)l * Dc * Dc;
    const unsigned short* W1t_l = W1t + (size_t)l * Dc * Fc;
    const unsigned short* W2t_l = W2t + (size_t)l * Fc * Dc;

    // fused QKV projection: [4096 x 3072]; V cols written direct to Vtb
    gemm256<<<dim3((Mc / 256) * (QKVN / 256)), dim3(512), 0, stream>>>(
        xb, Wqkvt_l, bqkv + l * QKVN, QKVb, Vtb, QKVN / 256, QKVN, Dc, 0);
    attn128<<<dim3(512), blk, 0, stream>>>(QKVb, Vtb, Ob);

    // attention out-proj: 8-phase split-K=4 bf16 partials, fused reduce+LN1
    gemm256_sk<4><<<dim3((Dc / 256) * (Mc / 256) * 4), dim3(512), 0, stream>>>(
        Ob, Wot_l, part, Dc / 256, Mc / 256, Dc, Dc);
    reduce_ln<4><<<dim3(Mc), blk, 0, stream>>>(
        part, bo + ob, xb, g1 + ob, be1 + ob, nullptr, xb);

    // FF1: [4096 x 4096]
    gemm256<<<dim3((Mc / 256) * (Fc / 256)), dim3(512), 0, stream>>>(
        xb, W1t_l, b1 + l * Fc, ff1, nullptr, Fc / 256, Fc, Dc, 1);

    // FF2: 8-phase split-K=4 bf16 partials, fused reduce+LN2
    gemm256_sk<4><<<dim3((Dc / 256) * (Mc / 256) * 4), dim3(512), 0, stream>>>(
        ff1, W2t_l, part, Dc / 256, Mc / 256, Dc, Fc);
    reduce_ln<4><<<dim3(Mc), blk, 0, stream>>>(
        part, b2 + ob, xb, g2 + ob, be2 + ob,
        (l == Lc - 1) ? (float*)d_out : nullptr, xb);
  }
}

// Round 17
// 1340.992 us; speedup vs baseline: 1.0018x; 1.0018x over previous
//
#include <hip/hip_runtime.h>
#include <hip/hip_bf16.h>

#define DEV static __device__ __forceinline__

typedef __attribute__((ext_vector_type(8))) short bf16x8;   // 8 bf16 = 4 VGPR (MFMA A/B frag)
typedef __attribute__((ext_vector_type(4))) float f32x4;    // MFMA C/D frag
typedef __attribute__((ext_vector_type(4))) unsigned short u16x4;
typedef __attribute__((ext_vector_type(4))) unsigned int u32x4;

constexpr int Lc = 6, Dc = 1024, Sc = 2048, Fc = 4096, Hc = 16, Bc = 2;
constexpr int Mc = Bc * Sc;   // 4096 activation rows
constexpr int QKVN = 3 * Dc;  // fused QKV width
constexpr float QSCALE = 0.18033688011112042f;  // log2(e)/8, folded into Wq/bq

DEV float bf2f(unsigned short u) {
  unsigned int x = ((unsigned int)u) << 16; float f;
  __builtin_memcpy(&f, &x, 4); return f;
}
DEV unsigned short f2bf(float f) {   // RNE
  unsigned int x; __builtin_memcpy(&x, &f, 4);
  x += 0x7fffu + ((x >> 16) & 1u);
  return (unsigned short)(x >> 16);
}
DEV unsigned int cvt_pk_bf16(float lo, float hi) {  // (bf16(hi)<<16)|bf16(lo), RNE
  unsigned int r;
  asm("v_cvt_pk_bf16_f32 %0, %1, %2" : "=v"(r) : "v"(lo), "v"(hi));
  return r;
}

typedef __attribute__((address_space(1))) unsigned int* gas_t;
typedef __attribute__((address_space(3))) unsigned int* las_t;
DEV void gload16(const void* g, void* l) {
  __builtin_amdgcn_global_load_lds((gas_t)g, (las_t)l, 16, 0, 0);
}

DEV int vperm(int k) {   // within 64; preserves k&3
  return ((k >> 5) << 5) + (((k >> 2) & 3) << 3) + (((k >> 4) & 1) << 2) + (k & 3);
}

// ------------------------------------------------- fused ALL-layer weight prep
// 64(n) x 256(k) per block, 4 sub-tiles of 64x64. Loads f32x4 (16B/lane),
// stores u16x4 (8B/lane). tile[64][65]: both phases ~2-way bank alias (free).
DEV void tr64v(const float* __restrict__ W, unsigned short* __restrict__ Wt,
               int Kd, int Nd, float scale, int bx, int by, int tid,
               float (*tile)[65])
{
  const int n0 = bx * 64;
#pragma unroll
  for (int s = 0; s < 4; ++s) {
    const int k0 = by * 256 + s * 64;
#pragma unroll
    for (int it = 0; it < 4; ++it) {
      int idx = it * 256 + tid;
      int k = idx >> 4, c0 = (idx & 15) * 4;
      *(f32x4*)&tile[k][c0] = *(const f32x4*)&W[(size_t)(k0 + k) * Nd + n0 + c0];
    }
    __syncthreads();
#pragma unroll
    for (int it = 0; it < 4; ++it) {
      int idx = it * 256 + tid;
      int n = idx >> 4, kc = (idx & 15) * 4;
      u16x4 o;
#pragma unroll
      for (int j = 0; j < 4; ++j) o[j] = f2bf(tile[kc + j][n] * scale);
      *(u16x4*)&Wt[(size_t)(n0 + n) * Kd + k0 + kc] = o;
    }
    __syncthreads();
  }
}

// Per layer 780 blocks: [0,256) 4x DxD (64 ea) | [256,512) W1 |
// [512,768) W2 | [768,780) bias pack.
__global__ __launch_bounds__(256) void prep_weights(
    const float* __restrict__ Wq, const float* __restrict__ Wk,
    const float* __restrict__ Wv, const float* __restrict__ Wo,
    const float* __restrict__ W1, const float* __restrict__ W2,
    const float* __restrict__ bq, const float* __restrict__ bk,
    const float* __restrict__ bv,
    unsigned short* __restrict__ Wqkvt, unsigned short* __restrict__ Wot,
    unsigned short* __restrict__ W1t, unsigned short* __restrict__ W2t,
    float* __restrict__ bqkv)
{
  __shared__ float tile[64][65];
  const int l = blockIdx.x / 780;
  const int id = blockIdx.x % 780;
  const int t = threadIdx.x;
  const size_t owD = (size_t)l * Dc * Dc, owF = (size_t)l * Dc * Fc;
  unsigned short* Wqkvt_l = Wqkvt + (size_t)l * 3 * Dc * Dc;
  unsigned short* Wot_l = Wot + (size_t)l * Dc * Dc;
  unsigned short* W1t_l = W1t + owF;
  unsigned short* W2t_l = W2t + owF;
  if (id < 256) {            // 4 DxD: bx in [0,16), by in [0,4)
    int which = id >> 6, lo = id & 63;
    int bx = lo & 15, by = lo >> 4;
    if (which == 0)      tr64v(Wq + owD, Wqkvt_l, Dc, Dc, QSCALE, bx, by, t, tile);
    else if (which == 1) tr64v(Wk + owD, Wqkvt_l + (size_t)Dc * Dc, Dc, Dc, 1.0f, bx, by, t, tile);
    else if (which == 2) tr64v(Wv + owD, Wqkvt_l + (size_t)2 * Dc * Dc, Dc, Dc, 1.0f, bx, by, t, tile);
    else                 tr64v(Wo + owD, Wot_l, Dc, Dc, 1.0f, bx, by, t, tile);
  } else if (id < 512) {     // W1 [1024 x 4096]: bx in [0,64), by in [0,4)
    int lo = id - 256;
    tr64v(W1 + owF, W1t_l, Dc, Fc, 1.0f, lo & 63, lo >> 6, t, tile);
  } else if (id < 768) {     // W2 [4096 x 1024]: bx in [0,16), by in [0,16)
    int lo = id - 512;
    tr64v(W2 + owF, W2t_l, Fc, Dc, 1.0f, lo & 15, lo >> 4, t, tile);
  } else {                   // bias pack
    int i = (id - 768) * 256 + t;
    const int ob = l * Dc;
    bqkv[l * QKVN + i] =
        (i < Dc) ? bq[ob + i] * QSCALE
                 : (i < 2 * Dc ? bk[ob + i - Dc] : bv[ob + i - 2 * Dc]);
  }
}

// ---------------------------------------------------------------- embed + PE
__global__ __launch_bounds__(256) void embed_kernel(
    const int* __restrict__ tokens, const float* __restrict__ emb,
    unsigned short* __restrict__ xb)
{
  const int bs = blockIdx.x;            // b*S + s
  const int s = bs & (Sc - 1);
  const int tok = tokens[bs];
  const int d0 = threadIdx.x * 4;
  f32x4 e4 = *(const f32x4*)(emb + (size_t)tok * Dc + d0);
  u16x4 vb;
#pragma unroll
  for (int j = 0; j < 4; ++j) {
    int d = d0 + j;
    float e = e4[j] * 32.0f;                             // sqrt(D)=32
    float fr = expf((float)(d & ~1) * (-9.210340371976184f / 1024.0f));
    float arg = (float)s * fr;
    float pe = (d & 1) ? cosf(arg) : sinf(arg);
    vb[j] = f2bf(e + pe);
  }
  *(u16x4*)(xb + (size_t)bs * Dc + d0) = vb;
}

// ------------------------------------------------------- 256x256 8-phase core
DEV void gemm256_core(const unsigned short* __restrict__ A,
                      const unsigned short* __restrict__ Bt,
                      unsigned short (*As)[256 * 64], unsigned short (*Bs)[256 * 64],
                      f32x4 (*acc)[4], int mTile, int nTile,
                      int Kstride, int k0, int nT, int t)
{
  const int lane = t & 63;
  const int g = lane >> 4, li = lane & 15;
  const int w = t >> 6;
  const int wm = w >> 2, wn = w & 3;
  const int trow = t >> 3, tslot = t & 7;
  const int asl = tslot ^ (trow & 7);
  int aoff[4];
#pragma unroll
  for (int q = 0; q < 4; ++q) {
    int R = (trow < 32) ? (q * 32 + trow) : (96 + q * 32 + trow);
    aoff[q] = (mTile + R) * Kstride + k0 + asl * 8;
  }
  int boff[4], bld[4];
#pragma unroll
  for (int k2 = 0; k2 < 4; ++k2) {
    int idx = k2 * 512 + t;
    int br = idx >> 3;
    int bs = (idx & 7) ^ (br & 7);
    boff[k2] = (nTile + br) * Kstride + k0 + bs * 8;
    bld[k2] = idx * 8;
  }

  auto stB = [&](int nb, int kt, int ph) {
    gload16(Bt + boff[ph * 2 + 0] + kt, &Bs[nb][bld[ph * 2 + 0]]);
    gload16(Bt + boff[ph * 2 + 1] + kt, &Bs[nb][bld[ph * 2 + 1]]);
  };
  auto stA = [&](int nb, int kt, int ph) {
    gload16(A + aoff[ph * 2 + 0] + kt, &As[nb][(ph * 2 + 0) * 4096 + t * 8]);
    gload16(A + aoff[ph * 2 + 1] + kt, &As[nb][(ph * 2 + 1) * 4096 + t * 8]);
  };

  // prologue: stage tile 0 fully
  stB(0, 0, 0); stB(0, 0, 1); stA(0, 0, 0); stA(0, 0, 1);
  asm volatile("s_waitcnt vmcnt(0)" ::: "memory");
  __builtin_amdgcn_s_barrier();

  int cur = 0;
  for (int tt = 0; tt < nT; ++tt) {
    const char* Ac = (const char*)As[cur];
    const char* Bc = (const char*)Bs[cur];
    const int nb = cur ^ 1;
    const int ktn = (tt + 1) << 6;
    const bool more = tt + 1 < nT;

    bf16x8 bfr[4][2];
#pragma unroll
    for (int ni = 0; ni < 4; ++ni) {
      const int rn = wn * 64 + ni * 16 + li;
#pragma unroll
      for (int ks = 0; ks < 2; ++ks) {
        const int kb = ks * 64 + (g << 4);
        bfr[ni][ks] = *(const bf16x8*)(Bc + rn * 128 + (kb ^ ((rn & 7) << 4)));
      }
    }

#pragma unroll
    for (int ph = 0; ph < 4; ++ph) {
      bf16x8 afr[2][2];
#pragma unroll
      for (int mi2 = 0; mi2 < 2; ++mi2) {
        const int rr = wm * 32 + mi2 * 16 + li;
#pragma unroll
        for (int ks = 0; ks < 2; ++ks) {
          const int kb = ks * 64 + (g << 4);
          afr[mi2][ks] = *(const bf16x8*)(Ac + ph * 8192 + rr * 128 + (kb ^ ((rr & 7) << 4)));
        }
      }
      if (more) {
        if (ph == 0)      stB(nb, ktn, 0);
        else if (ph == 1) stB(nb, ktn, 1);
        else if (ph == 2) stA(nb, ktn, 0);
        else              stA(nb, ktn, 1);
      }
      __builtin_amdgcn_s_barrier();
      __builtin_amdgcn_s_setprio(1);
#pragma unroll
      for (int mi2 = 0; mi2 < 2; ++mi2)
#pragma unroll
        for (int ni = 0; ni < 4; ++ni)
#pragma unroll
          for (int ks = 0; ks < 2; ++ks)
            acc[ph * 2 + mi2][ni] = __builtin_amdgcn_mfma_f32_16x16x32_bf16(
                afr[mi2][ks], bfr[ni][ks], acc[ph * 2 + mi2][ni], 0, 0, 0);
      __builtin_amdgcn_s_setprio(0);
      if (ph == 0)      asm volatile("s_waitcnt vmcnt(4)" ::: "memory");
      else if (ph == 1) asm volatile("s_waitcnt vmcnt(5)" ::: "memory");
      else if (ph == 2) asm volatile("s_waitcnt vmcnt(6)" ::: "memory");
      else              asm volatile("s_waitcnt vmcnt(3)" ::: "memory");
      __builtin_amdgcn_s_barrier();
    }
    cur ^= 1;
  }
}

// full-K 256^2 GEMM + bias/relu epilogue; for QKV, V-columns (c>=2048) are
// written transposed+vperm'd directly to Vt (replacing transpose_v).
__global__ __launch_bounds__(512) void gemm256(
    const unsigned short* __restrict__ A, const unsigned short* __restrict__ Bt,
    const float* __restrict__ bias, unsigned short* __restrict__ outB,
    unsigned short* __restrict__ Vt, int gx, int Ndim, int Kdim, int relu)
{
  __shared__ alignas(16) unsigned short As[2][256 * 64];
  __shared__ alignas(16) unsigned short Bs[2][256 * 64];
  const int t = threadIdx.x;
  const int lane = t & 63, w = t >> 6;
  const int wm = w >> 2, wn = w & 3;
  const int g = lane >> 4, li = lane & 15;
  const int nwg = gridDim.x, flat = blockIdx.x;
  const int swz = (flat & 7) * (nwg >> 3) + (flat >> 3);
  const int mTile = (swz / gx) * 256;
  const int nTile = (swz % gx) * 256;

  f32x4 acc[8][4] = {};
  gemm256_core(A, Bt, As, Bs, acc, mTile, nTile, Kdim, 0, Kdim >> 6, t);

  const bool vblk = (Vt != nullptr) && (nTile >= 2 * Dc);
#pragma unroll
  for (int mi = 0; mi < 8; ++mi) {
#pragma unroll
    for (int ni = 0; ni < 4; ++ni) {
      const int c = nTile + wn * 64 + ni * 16 + li;
      const float bvv = bias[c];
      if (!vblk) {
#pragma unroll
        for (int j = 0; j < 4; ++j) {
          const int r = mTile + wm * 128 + mi * 16 + g * 4 + j;
          float v = acc[mi][ni][j] + bvv;
          if (relu) v = fmaxf(v, 0.0f);
          outB[(size_t)r * Ndim + c] = f2bf(v);
        }
      } else {
        const int r0 = mTile + wm * 128 + mi * 16 + g * 4;   // %4 == 0
        const int b = r0 >> 11, s0 = r0 & 2047;
        const int sp = (s0 & ~63) + vperm(s0 & 63);          // contiguous for j
        u16x4 ov;
#pragma unroll
        for (int j = 0; j < 4; ++j) ov[j] = f2bf(acc[mi][ni][j] + bvv);
        *(u16x4*)(Vt + ((size_t)(b * Dc + (c - 2 * Dc))) * Sc + sp) = ov;
      }
    }
  }
}

// split-K 256^2 GEMM: writes bf16 partials part[z][M][N]. grid=gx*gy*SPLIT.
template<int SPLIT>
__global__ __launch_bounds__(512) void gemm256_sk(
    const unsigned short* __restrict__ A, const unsigned short* __restrict__ Bt,
    unsigned short* __restrict__ part, int gx, int gy, int Ndim, int Ktot)
{
  __shared__ alignas(16) unsigned short As[2][256 * 64];
  __shared__ alignas(16) unsigned short Bs[2][256 * 64];
  const int t = threadIdx.x;
  const int lane = t & 63, w = t >> 6;
  const int wm = w >> 2, wn = w & 3;
  const int g = lane >> 4, li = lane & 15;
  const int nwg = gridDim.x, flat = blockIdx.x;
  const int swz = (flat & 7) * (nwg >> 3) + (flat >> 3);
  const int nTile = (swz % gx) * 256;
  const int mTile = ((swz / gx) % gy) * 256;
  const int z = swz / (gx * gy);
  const int Kseg = Ktot / SPLIT;

  f32x4 acc[8][4] = {};
  gemm256_core(A, Bt, As, Bs, acc, mTile, nTile, Ktot, z * Kseg, Kseg >> 6, t);

  unsigned short* po = part + (size_t)z * Mc * Ndim;
#pragma unroll
  for (int mi = 0; mi < 8; ++mi)
#pragma unroll
    for (int ni = 0; ni < 4; ++ni) {
      const int c = nTile + wn * 64 + ni * 16 + li;
#pragma unroll
      for (int j = 0; j < 4; ++j) {
        const int r = mTile + wm * 128 + mi * 16 + g * 4 + j;
        po[(size_t)r * Ndim + c] = f2bf(acc[mi][ni][j]);
      }
    }
}

// ---------------------------------------------------------------- attention
// QBLK=128, 512 blocks (XCD-swizzled), 4 waves split 2x2 over (q,k):
// wave (wq,wk) owns q rows [wq*64,+64) x k range [wk*1024,+1024).
// Each K/V LDS fragment feeds 4 MFMAs (2x the q-split version) -> per-wave
// LDS traffic halves; 16 barriers instead of 32. Softmax (no-max) is additive
// in k, so the two k-halves merge via one 32KB LDS reduction in the epilogue
// (overlaying the dead K buffers). LDS 80KB -> 2 blocks/CU.
__global__ __launch_bounds__(256, 2) void attn128(
    const unsigned short* __restrict__ QKV, const unsigned short* __restrict__ Vt,
    unsigned short* __restrict__ O)
{
  __shared__ alignas(16) char smem[80 * 1024];
  unsigned short* Qs  = (unsigned short*)smem;                 // 16 KB
  unsigned short* KsB = (unsigned short*)(smem + 16 * 1024);   // 32 KB: [dbuf*2+col]
  unsigned short* VsB = (unsigned short*)(smem + 48 * 1024);   // 32 KB

  const int t = threadIdx.x;
  const int lane = t & 63, w = t >> 6;
  const int wq = w >> 1, wk = w & 1;
  const int g = lane >> 4, li = lane & 15;
  const int flat = blockIdx.x;
  const int idx = ((flat & 7) << 6) | (flat >> 3);     // 512 blocks, 64/XCD
  const int qb = idx & 15, bh = idx >> 4;              // 16 q-blocks per head
  const int b = bh >> 4, h = bh & 15;

  const size_t qbase  = ((size_t)(b * Sc + qb * 128)) * QKVN + h * 64;
  const size_t kbase0 = ((size_t)b * Sc) * QKVN + Dc + h * 64;
  const size_t vbase0 = ((size_t)(b * Dc + h * 64)) * Sc;

#pragma unroll
  for (int i = 0; i < 4; ++i) {
    int idx2 = i * 256 + t, row = idx2 >> 3, sl = (idx2 & 7) ^ (row & 7);
    gload16(QKV + qbase + (size_t)row * QKVN + sl * 8, &Qs[idx2 * 8]);
  }
  const unsigned short* kg[2];
  const unsigned short* vg[2];
  int loff[2];
#pragma unroll
  for (int i = 0; i < 2; ++i) {
    int idx2 = i * 256 + t, row = idx2 >> 3, sl = (idx2 & 7) ^ (row & 7);
    kg[i] = QKV + kbase0 + (size_t)row * QKVN + sl * 8;
    vg[i] = Vt + vbase0 + (size_t)row * Sc + sl * 8;
    loff[i] = idx2 * 8;
  }
  const size_t KC = (size_t)1024 * QKVN;   // col-1 K offset (k += 1024)

  // prologue: stage chunk 0 of both k-columns into dbuf 0
#pragma unroll
  for (int c = 0; c < 2; ++c) {
    gload16(kg[0] + c * KC, &KsB[(0 * 2 + c) * 4096 + loff[0]]);
    gload16(kg[1] + c * KC, &KsB[(0 * 2 + c) * 4096 + loff[1]]);
    gload16(vg[0] + c * 1024, &VsB[(0 * 2 + c) * 4096 + loff[0]]);
    gload16(vg[1] + c * 1024, &VsB[(0 * 2 + c) * 4096 + loff[1]]);
  }
  kg[0] += 64 * QKVN; kg[1] += 64 * QKVN;
  vg[0] += 64;        vg[1] += 64;
  __syncthreads();   // Q + chunk0 (both cols) resident

  bf16x8 qf[4][2];
#pragma unroll
  for (int qi = 0; qi < 4; ++qi) {
    const int rq = wq * 64 + qi * 16 + li;
#pragma unroll
    for (int ks = 0; ks < 2; ++ks) {
      const int kb = ks * 64 + (g << 4);
      qf[qi][ks] = *(const bf16x8*)((const char*)Qs + rq * 128 + (kb ^ ((rq & 7) << 4)));
    }
  }
  bf16x8 ones;
#pragma unroll
  for (int e = 0; e < 8; ++e) ones[e] = (short)0x3F80;  // bf16 1.0

  f32x4 acc_o[4][4] = {};
  f32x4 acc_l[4] = {};

  for (int tt = 0; tt < 16; ++tt) {
    const int cur = tt & 1;
    if (tt + 1 < 16) {
      const int nb = cur ^ 1;
#pragma unroll
      for (int c = 0; c < 2; ++c) {
        gload16(kg[0] + c * KC, &KsB[(nb * 2 + c) * 4096 + loff[0]]);
        gload16(kg[1] + c * KC, &KsB[(nb * 2 + c) * 4096 + loff[1]]);
        gload16(vg[0] + c * 1024, &VsB[(nb * 2 + c) * 4096 + loff[0]]);
        gload16(vg[1] + c * 1024, &VsB[(nb * 2 + c) * 4096 + loff[1]]);
      }
      kg[0] += 64 * QKVN; kg[1] += 64 * QKVN;
      vg[0] += 64;        vg[1] += 64;
    }
    const char* Kc = (const char*)(KsB + (cur * 2 + wk) * 4096);
    const char* Vc = (const char*)(VsB + (cur * 2 + wk) * 4096);

    // swapped QK^T: each K fragment feeds all 4 q-subtiles
    f32x4 accs[4][4] = {};
#pragma unroll
    for (int ks = 0; ks < 2; ++ks) {
      const int kb = ks * 64 + (g << 4);
#pragma unroll
      for (int ni = 0; ni < 4; ++ni) {
        const int rk = ni * 16 + li;
        bf16x8 ak = *(const bf16x8*)(Kc + rk * 128 + (kb ^ ((rk & 7) << 4)));
#pragma unroll
        for (int qi = 0; qi < 4; ++qi)
          accs[qi][ni] = __builtin_amdgcn_mfma_f32_16x16x32_bf16(
              ak, qf[qi][ks], accs[qi][ni], 0, 0, 0);
      }
    }

    unsigned int pk[4][4][2];
#pragma unroll
    for (int qi = 0; qi < 4; ++qi)
#pragma unroll
      for (int ni = 0; ni < 4; ++ni) {
        float p0 = exp2f(accs[qi][ni][0]);
        float p1 = exp2f(accs[qi][ni][1]);
        float p2 = exp2f(accs[qi][ni][2]);
        float p3 = exp2f(accs[qi][ni][3]);
        pk[qi][ni][0] = cvt_pk_bf16(p0, p1);
        pk[qi][ni][1] = cvt_pk_bf16(p2, p3);
      }

#pragma unroll
    for (int ks = 0; ks < 2; ++ks) {
      bf16x8 ap[4];
#pragma unroll
      for (int qi = 0; qi < 4; ++qi) {
        u32x4 av = {pk[qi][2 * ks][0], pk[qi][2 * ks][1],
                    pk[qi][2 * ks + 1][0], pk[qi][2 * ks + 1][1]};
        ap[qi] = __builtin_bit_cast(bf16x8, av);
        acc_l[qi] = __builtin_amdgcn_mfma_f32_16x16x32_bf16(ap[qi], ones, acc_l[qi], 0, 0, 0);
      }
      const int kb = ks * 64 + (g << 4);
#pragma unroll
      for (int ni = 0; ni < 4; ++ni) {
        const int rd = ni * 16 + li;
        bf16x8 bv = *(const bf16x8*)(Vc + rd * 128 + (kb ^ ((rd & 7) << 4)));
#pragma unroll
        for (int qi = 0; qi < 4; ++qi)
          acc_o[qi][ni] = __builtin_amdgcn_mfma_f32_16x16x32_bf16(
              ap[qi], bv, acc_o[qi][ni], 0, 0, 0);
      }
    }

    __syncthreads();
  }

  // cross-wk reduction: wk=1 dumps partials into dead K/V LDS; wk=0 merges.
  float* red  = (float*)(smem + 16 * 1024);   // 32 KB: acc_o partials
  float* red2 = (float*)(smem + 48 * 1024);   // 512 B: acc_l partials
  if (wk == 1) {
#pragma unroll
    for (int qi = 0; qi < 4; ++qi) {
#pragma unroll
      for (int ni = 0; ni < 4; ++ni)
#pragma unroll
        for (int j = 0; j < 4; ++j)
          red[((((wq * 4 + qi) * 4 + ni) * 16) + g * 4 + j) * 16 + li] = acc_o[qi][ni][j];
      if (li == 0)
#pragma unroll
        for (int j = 0; j < 4; ++j)
          red2[(wq * 4 + qi) * 16 + g * 4 + j] = acc_l[qi][j];
    }
  }
  __syncthreads();
  if (wk == 0) {
    const size_t obase = ((size_t)(b * Sc + qb * 128)) * Dc + h * 64;
#pragma unroll
    for (int qi = 0; qi < 4; ++qi) {
      float denom[4];
#pragma unroll
      for (int j = 0; j < 4; ++j)
        denom[j] = 1.0f / (acc_l[qi][j] + red2[(wq * 4 + qi) * 16 + g * 4 + j]);
#pragma unroll
      for (int ni = 0; ni < 4; ++ni)
#pragma unroll
        for (int j = 0; j < 4; ++j) {
          float v = acc_o[qi][ni][j] +
                    red[((((wq * 4 + qi) * 4 + ni) * 16) + g * 4 + j) * 16 + li];
          int q = wq * 64 + qi * 16 + g * 4 + j;
          O[obase + (size_t)q * Dc + ni * 16 + li] = f2bf(v * denom[j]);
        }
    }
  }
}

// ------------------------- split-K (bf16) reduce + layernorm, bf16 residual
template<int SPLIT>
__global__ __launch_bounds__(256) void reduce_ln(
    const unsigned short* __restrict__ part, const float* __restrict__ bias,
    const unsigned short* __restrict__ resb, const float* __restrict__ g,
    const float* __restrict__ be, float* __restrict__ fout,
    unsigned short* __restrict__ xb_out)
{
  const int row = blockIdx.x, t = threadIdx.x;
  const size_t off = (size_t)row * Dc + t * 4;
  u16x4 rv = *(const u16x4*)(resb + off);
  f32x4 v;
#pragma unroll
  for (int j = 0; j < 4; ++j) v[j] = bf2f(rv[j]);
  v += *(const f32x4*)(bias + t * 4);
#pragma unroll
  for (int s = 0; s < SPLIT; ++s) {
    u16x4 pv = *(const u16x4*)(part + (size_t)s * Mc * Dc + off);
#pragma unroll
    for (int j = 0; j < 4; ++j) v[j] += bf2f(pv[j]);
  }

  float sm = v[0] + v[1] + v[2] + v[3];
  float q = v[0]*v[0] + v[1]*v[1] + v[2]*v[2] + v[3]*v[3];
#pragma unroll
  for (int o = 32; o; o >>= 1) {
    sm += __shfl_down(sm, o);
    q += __shfl_down(q, o);
  }
  __shared__ float rs_[4], rq_[4];
  const int lane = t & 63, w = t >> 6;
  if (lane == 0) { rs_[w] = sm; rq_[w] = q; }
  __syncthreads();
  sm = rs_[0] + rs_[1] + rs_[2] + rs_[3];
  q = rq_[0] + rq_[1] + rq_[2] + rq_[3];
  const float mu = sm * (1.0f / 1024.0f);
  const float var = q * (1.0f / 1024.0f) - mu * mu;
  const float rstd = rsqrtf(var + 1e-5f);
  f32x4 vg = *(const f32x4*)(g + t * 4);
  f32x4 vb = *(const f32x4*)(be + t * 4);
  f32x4 o; u16x4 ob;
#pragma unroll
  for (int j = 0; j < 4; ++j) {
    float val = (v[j] - mu) * rstd * vg[j] + vb[j];
    o[j] = val; ob[j] = f2bf(val);
  }
  if (fout) *(f32x4*)(fout + off) = o;
  *(u16x4*)(xb_out + off) = ob;
}

// ---------------------------------------------------------------- launch
extern "C" void kernel_launch(void* const* d_in, const int* in_sizes, int n_in,
                              void* d_out, int out_size, void* d_ws, size_t ws_size,
                              hipStream_t stream)
{
  (void)in_sizes; (void)n_in; (void)out_size; (void)ws_size;
  const int*   tokens = (const int*)d_in[0];
  const float* emb = (const float*)d_in[1];
  const float* Wq = (const float*)d_in[2];
  const float* bq = (const float*)d_in[3];
  const float* Wk = (const float*)d_in[4];
  const float* bk = (const float*)d_in[5];
  const float* Wv = (const float*)d_in[6];
  const float* bv = (const float*)d_in[7];
  const float* Wo = (const float*)d_in[8];
  const float* bo = (const float*)d_in[9];
  const float* W1 = (const float*)d_in[10];
  const float* b1 = (const float*)d_in[11];
  const float* W2 = (const float*)d_in[12];
  const float* b2 = (const float*)d_in[13];
  const float* g1 = (const float*)d_in[14];
  const float* be1 = (const float*)d_in[15];
  const float* g2 = (const float*)d_in[16];
  const float* be2 = (const float*)d_in[17];

  char* p = (char*)d_ws;
  auto take = [&](size_t bytes) { char* q = p; p += bytes; return q; };
  // ALL-layer transposed weights (prepped once, before the layer loop)
  unsigned short* Wqkvt = (unsigned short*)take((size_t)Lc * 3 * Dc * Dc * 2); // 36 MB
  unsigned short* Wot = (unsigned short*)take((size_t)Lc * Dc * Dc * 2);       // 12 MB
  unsigned short* W1t = (unsigned short*)take((size_t)Lc * Dc * Fc * 2);       // 48 MB
  unsigned short* W2t = (unsigned short*)take((size_t)Lc * Fc * Dc * 2);       // 48 MB
  float*          bqkv = (float*)take((size_t)Lc * QKVN * 4);
  unsigned short* xb  = (unsigned short*)take((size_t)Mc * Dc * 2);
  unsigned short* QKVb = (unsigned short*)take((size_t)Mc * QKVN * 2);
  unsigned short* Vtb = (unsigned short*)take((size_t)Bc * Dc * Sc * 2);
  unsigned short* Ob  = (unsigned short*)take((size_t)Mc * Dc * 2);
  unsigned short* ff1 = (unsigned short*)take((size_t)Mc * Fc * 2);
  // split-K bf16 partials (4 x 8 MB) overlay QKVb+Vtb (dead after attn)
  unsigned short* part = QKVb;

  dim3 blk(256);
  prep_weights<<<dim3(Lc * 780), blk, 0, stream>>>(
      Wq, Wk, Wv, Wo, W1, W2, bq, bk, bv, Wqkvt, Wot, W1t, W2t, bqkv);
  embed_kernel<<<dim3(Mc), blk, 0, stream>>>(tokens, emb, xb);

  for (int l = 0; l < Lc; ++l) {
    const int ob = l * Dc;
    const unsigned short* Wqkvt_l = Wqkvt + (size_t)l * 3 * Dc * Dc;
    const unsigned short* Wot_l = Wot + (size_t)l * Dc * Dc;
    const unsigned short* W1t_l = W1t + (size_t)l * Dc * Fc;
    const unsigned short* W2t_l = W2t + (size_t)l * Fc * Dc;

    // fused QKV projection: [4096 x 3072]; V cols written direct to Vtb
    gemm256<<<dim3((Mc / 256) * (QKVN / 256)), dim3(512), 0, stream>>>(
        xb, Wqkvt_l, bqkv + l * QKVN, QKVb, Vtb, QKVN / 256, QKVN, Dc, 0);
    attn128<<<dim3(512), blk, 0, stream>>>(QKVb, Vtb, Ob);

    // attention out-proj: 8-phase split-K=4 bf16 partials, fused reduce+LN1
    gemm256_sk<4><<<dim3((Dc / 256) * (Mc / 256) * 4), dim3(512), 0, stream>>>(
        Ob, Wot_l, part, Dc / 256, Mc / 256, Dc, Dc);
    reduce_ln<4><<<dim3(Mc), blk, 0, stream>>>(
        part, bo + ob, xb, g1 + ob, be1 + ob, nullptr, xb);

    // FF1: [4096 x 4096]
    gemm256<<<dim3((Mc / 256) * (Fc / 256)), dim3(512), 0, stream>>>(
        xb, W1t_l, b1 + l * Fc, ff1, nullptr, Fc / 256, Fc, Dc, 1);

    // FF2: 8-phase split-K=4 bf16 partials, fused reduce+LN2
    gemm256_sk<4><<<dim3((Dc / 256) * (Mc / 256) * 4), dim3(512), 0, stream>>>(
        ff1, W2t_l, part, Dc / 256, Mc / 256, Dc, Fc);
    reduce_ln<4><<<dim3(Mc), blk, 0, stream>>>(
        part, b2 + ob, xb, g2 + ob, be2 + ob,
        (l == Lc - 1) ? (float*)d_out : nullptr, xb);
  }
}

// Round 18
// 1339.337 us; speedup vs baseline: 1.0031x; 1.0012x over previous
//
#include <hip/hip_runtime.h>
#include <hip/hip_bf16.h>

#define DEV static __device__ __forceinline__

typedef __attribute__((ext_vector_type(8))) short bf16x8;   // 8 bf16 = 4 VGPR (MFMA A/B frag)
typedef __attribute__((ext_vector_type(4))) float f32x4;    // MFMA C/D frag
typedef __attribute__((ext_vector_type(4))) unsigned short u16x4;
typedef __attribute__((ext_vector_type(4))) unsigned int u32x4;

constexpr int Lc = 6, Dc = 1024, Sc = 2048, Fc = 4096, Hc = 16, Bc = 2;
constexpr int Mc = Bc * Sc;   // 4096 activation rows
constexpr int QKVN = 3 * Dc;  // fused QKV width
constexpr float QSCALE = 0.18033688011112042f;  // log2(e)/8, folded into Wq/bq

DEV float bf2f(unsigned short u) {
  unsigned int x = ((unsigned int)u) << 16; float f;
  __builtin_memcpy(&f, &x, 4); return f;
}
DEV unsigned short f2bf(float f) {   // RNE
  unsigned int x; __builtin_memcpy(&x, &f, 4);
  x += 0x7fffu + ((x >> 16) & 1u);
  return (unsigned short)(x >> 16);
}
DEV unsigned int cvt_pk_bf16(float lo, float hi) {  // (bf16(hi)<<16)|bf16(lo), RNE
  unsigned int r;
  asm("v_cvt_pk_bf16_f32 %0, %1, %2" : "=v"(r) : "v"(lo), "v"(hi));
  return r;
}

typedef __attribute__((address_space(1))) unsigned int* gas_t;
typedef __attribute__((address_space(3))) unsigned int* las_t;
DEV void gload16(const void* g, void* l) {
  __builtin_amdgcn_global_load_lds((gas_t)g, (las_t)l, 16, 0, 0);
}

DEV int vperm(int k) {   // within 64; preserves k&3
  return ((k >> 5) << 5) + (((k >> 2) & 3) << 3) + (((k >> 4) & 1) << 2) + (k & 3);
}

// ------------------------------------------------- fused ALL-layer weight prep
// 64(n) x 256(k) per block, 4 sub-tiles of 64x64. Loads f32x4 (16B/lane),
// stores u16x4 (8B/lane). tile[64][65]: both phases ~2-way bank alias (free).
DEV void tr64v(const float* __restrict__ W, unsigned short* __restrict__ Wt,
               int Kd, int Nd, float scale, int bx, int by, int tid,
               float (*tile)[65])
{
  const int n0 = bx * 64;
#pragma unroll
  for (int s = 0; s < 4; ++s) {
    const int k0 = by * 256 + s * 64;
#pragma unroll
    for (int it = 0; it < 4; ++it) {
      int idx = it * 256 + tid;
      int k = idx >> 4, c0 = (idx & 15) * 4;
      *(f32x4*)&tile[k][c0] = *(const f32x4*)&W[(size_t)(k0 + k) * Nd + n0 + c0];
    }
    __syncthreads();
#pragma unroll
    for (int it = 0; it < 4; ++it) {
      int idx = it * 256 + tid;
      int n = idx >> 4, kc = (idx & 15) * 4;
      u16x4 o;
#pragma unroll
      for (int j = 0; j < 4; ++j) o[j] = f2bf(tile[kc + j][n] * scale);
      *(u16x4*)&Wt[(size_t)(n0 + n) * Kd + k0 + kc] = o;
    }
    __syncthreads();
  }
}

// Per layer 780 blocks: [0,256) 4x DxD (64 ea) | [256,512) W1 |
// [512,768) W2 | [768,780) bias pack.
__global__ __launch_bounds__(256) void prep_weights(
    const float* __restrict__ Wq, const float* __restrict__ Wk,
    const float* __restrict__ Wv, const float* __restrict__ Wo,
    const float* __restrict__ W1, const float* __restrict__ W2,
    const float* __restrict__ bq, const float* __restrict__ bk,
    const float* __restrict__ bv,
    unsigned short* __restrict__ Wqkvt, unsigned short* __restrict__ Wot,
    unsigned short* __restrict__ W1t, unsigned short* __restrict__ W2t,
    float* __restrict__ bqkv)
{
  __shared__ float tile[64][65];
  const int l = blockIdx.x / 780;
  const int id = blockIdx.x % 780;
  const int t = threadIdx.x;
  const size_t owD = (size_t)l * Dc * Dc, owF = (size_t)l * Dc * Fc;
  unsigned short* Wqkvt_l = Wqkvt + (size_t)l * 3 * Dc * Dc;
  unsigned short* Wot_l = Wot + (size_t)l * Dc * Dc;
  unsigned short* W1t_l = W1t + owF;
  unsigned short* W2t_l = W2t + owF;
  if (id < 256) {            // 4 DxD: bx in [0,16), by in [0,4)
    int which = id >> 6, lo = id & 63;
    int bx = lo & 15, by = lo >> 4;
    if (which == 0)      tr64v(Wq + owD, Wqkvt_l, Dc, Dc, QSCALE, bx, by, t, tile);
    else if (which == 1) tr64v(Wk + owD, Wqkvt_l + (size_t)Dc * Dc, Dc, Dc, 1.0f, bx, by, t, tile);
    else if (which == 2) tr64v(Wv + owD, Wqkvt_l + (size_t)2 * Dc * Dc, Dc, Dc, 1.0f, bx, by, t, tile);
    else                 tr64v(Wo + owD, Wot_l, Dc, Dc, 1.0f, bx, by, t, tile);
  } else if (id < 512) {     // W1 [1024 x 4096]: bx in [0,64), by in [0,4)
    int lo = id - 256;
    tr64v(W1 + owF, W1t_l, Dc, Fc, 1.0f, lo & 63, lo >> 6, t, tile);
  } else if (id < 768) {     // W2 [4096 x 1024]: bx in [0,16), by in [0,16)
    int lo = id - 512;
    tr64v(W2 + owF, W2t_l, Fc, Dc, 1.0f, lo & 15, lo >> 4, t, tile);
  } else {                   // bias pack
    int i = (id - 768) * 256 + t;
    const int ob = l * Dc;
    bqkv[l * QKVN + i] =
        (i < Dc) ? bq[ob + i] * QSCALE
                 : (i < 2 * Dc ? bk[ob + i - Dc] : bv[ob + i - 2 * Dc]);
  }
}

// ---------------------------------------------------------------- embed + PE
__global__ __launch_bounds__(256) void embed_kernel(
    const int* __restrict__ tokens, const float* __restrict__ emb,
    unsigned short* __restrict__ xb)
{
  const int bs = blockIdx.x;            // b*S + s
  const int s = bs & (Sc - 1);
  const int tok = tokens[bs];
  const int d0 = threadIdx.x * 4;
  f32x4 e4 = *(const f32x4*)(emb + (size_t)tok * Dc + d0);
  u16x4 vb;
#pragma unroll
  for (int j = 0; j < 4; ++j) {
    int d = d0 + j;
    float e = e4[j] * 32.0f;                             // sqrt(D)=32
    float fr = expf((float)(d & ~1) * (-9.210340371976184f / 1024.0f));
    float arg = (float)s * fr;
    float pe = (d & 1) ? cosf(arg) : sinf(arg);
    vb[j] = f2bf(e + pe);
  }
  *(u16x4*)(xb + (size_t)bs * Dc + d0) = vb;
}

// ------------------------------------------------------- 256x256 8-phase core
DEV void gemm256_core(const unsigned short* __restrict__ A,
                      const unsigned short* __restrict__ Bt,
                      unsigned short (*As)[256 * 64], unsigned short (*Bs)[256 * 64],
                      f32x4 (*acc)[4], int mTile, int nTile,
                      int Kstride, int k0, int nT, int t)
{
  const int lane = t & 63;
  const int g = lane >> 4, li = lane & 15;
  const int w = t >> 6;
  const int wm = w >> 2, wn = w & 3;
  const int trow = t >> 3, tslot = t & 7;
  const int asl = tslot ^ (trow & 7);
  int aoff[4];
#pragma unroll
  for (int q = 0; q < 4; ++q) {
    int R = (trow < 32) ? (q * 32 + trow) : (96 + q * 32 + trow);
    aoff[q] = (mTile + R) * Kstride + k0 + asl * 8;
  }
  int boff[4], bld[4];
#pragma unroll
  for (int k2 = 0; k2 < 4; ++k2) {
    int idx = k2 * 512 + t;
    int br = idx >> 3;
    int bs = (idx & 7) ^ (br & 7);
    boff[k2] = (nTile + br) * Kstride + k0 + bs * 8;
    bld[k2] = idx * 8;
  }

  auto stB = [&](int nb, int kt, int ph) {
    gload16(Bt + boff[ph * 2 + 0] + kt, &Bs[nb][bld[ph * 2 + 0]]);
    gload16(Bt + boff[ph * 2 + 1] + kt, &Bs[nb][bld[ph * 2 + 1]]);
  };
  auto stA = [&](int nb, int kt, int ph) {
    gload16(A + aoff[ph * 2 + 0] + kt, &As[nb][(ph * 2 + 0) * 4096 + t * 8]);
    gload16(A + aoff[ph * 2 + 1] + kt, &As[nb][(ph * 2 + 1) * 4096 + t * 8]);
  };

  // prologue: stage tile 0 fully
  stB(0, 0, 0); stB(0, 0, 1); stA(0, 0, 0); stA(0, 0, 1);
  asm volatile("s_waitcnt vmcnt(0)" ::: "memory");
  __builtin_amdgcn_s_barrier();

  int cur = 0;
  for (int tt = 0; tt < nT; ++tt) {
    const char* Ac = (const char*)As[cur];
    const char* Bc = (const char*)Bs[cur];
    const int nb = cur ^ 1;
    const int ktn = (tt + 1) << 6;
    const bool more = tt + 1 < nT;

    bf16x8 bfr[4][2];
#pragma unroll
    for (int ni = 0; ni < 4; ++ni) {
      const int rn = wn * 64 + ni * 16 + li;
#pragma unroll
      for (int ks = 0; ks < 2; ++ks) {
        const int kb = ks * 64 + (g << 4);
        bfr[ni][ks] = *(const bf16x8*)(Bc + rn * 128 + (kb ^ ((rn & 7) << 4)));
      }
    }

#pragma unroll
    for (int ph = 0; ph < 4; ++ph) {
      bf16x8 afr[2][2];
#pragma unroll
      for (int mi2 = 0; mi2 < 2; ++mi2) {
        const int rr = wm * 32 + mi2 * 16 + li;
#pragma unroll
        for (int ks = 0; ks < 2; ++ks) {
          const int kb = ks * 64 + (g << 4);
          afr[mi2][ks] = *(const bf16x8*)(Ac + ph * 8192 + rr * 128 + (kb ^ ((rr & 7) << 4)));
        }
      }
      if (more) {
        if (ph == 0)      stB(nb, ktn, 0);
        else if (ph == 1) stB(nb, ktn, 1);
        else if (ph == 2) stA(nb, ktn, 0);
        else              stA(nb, ktn, 1);
      }
      __builtin_amdgcn_s_barrier();
      __builtin_amdgcn_s_setprio(1);
#pragma unroll
      for (int mi2 = 0; mi2 < 2; ++mi2)
#pragma unroll
        for (int ni = 0; ni < 4; ++ni)
#pragma unroll
          for (int ks = 0; ks < 2; ++ks)
            acc[ph * 2 + mi2][ni] = __builtin_amdgcn_mfma_f32_16x16x32_bf16(
                afr[mi2][ks], bfr[ni][ks], acc[ph * 2 + mi2][ni], 0, 0, 0);
      __builtin_amdgcn_s_setprio(0);
      if (ph == 0)      asm volatile("s_waitcnt vmcnt(4)" ::: "memory");
      else if (ph == 1) asm volatile("s_waitcnt vmcnt(5)" ::: "memory");
      else if (ph == 2) asm volatile("s_waitcnt vmcnt(6)" ::: "memory");
      else              asm volatile("s_waitcnt vmcnt(3)" ::: "memory");
      __builtin_amdgcn_s_barrier();
    }
    cur ^= 1;
  }
}

// full-K 256^2 GEMM + bias/relu epilogue; for QKV, V-columns (c>=2048) are
// written transposed+vperm'd directly to Vt (replacing transpose_v).
__global__ __launch_bounds__(512) void gemm256(
    const unsigned short* __restrict__ A, const unsigned short* __restrict__ Bt,
    const float* __restrict__ bias, unsigned short* __restrict__ outB,
    unsigned short* __restrict__ Vt, int gx, int Ndim, int Kdim, int relu)
{
  __shared__ alignas(16) unsigned short As[2][256 * 64];
  __shared__ alignas(16) unsigned short Bs[2][256 * 64];
  const int t = threadIdx.x;
  const int lane = t & 63, w = t >> 6;
  const int wm = w >> 2, wn = w & 3;
  const int g = lane >> 4, li = lane & 15;
  const int nwg = gridDim.x, flat = blockIdx.x;
  const int swz = (flat & 7) * (nwg >> 3) + (flat >> 3);
  const int mTile = (swz / gx) * 256;
  const int nTile = (swz % gx) * 256;

  f32x4 acc[8][4] = {};
  gemm256_core(A, Bt, As, Bs, acc, mTile, nTile, Kdim, 0, Kdim >> 6, t);

  const bool vblk = (Vt != nullptr) && (nTile >= 2 * Dc);
#pragma unroll
  for (int mi = 0; mi < 8; ++mi) {
#pragma unroll
    for (int ni = 0; ni < 4; ++ni) {
      const int c = nTile + wn * 64 + ni * 16 + li;
      const float bvv = bias[c];
      if (!vblk) {
#pragma unroll
        for (int j = 0; j < 4; ++j) {
          const int r = mTile + wm * 128 + mi * 16 + g * 4 + j;
          float v = acc[mi][ni][j] + bvv;
          if (relu) v = fmaxf(v, 0.0f);
          outB[(size_t)r * Ndim + c] = f2bf(v);
        }
      } else {
        const int r0 = mTile + wm * 128 + mi * 16 + g * 4;   // %4 == 0
        const int b = r0 >> 11, s0 = r0 & 2047;
        const int sp = (s0 & ~63) + vperm(s0 & 63);          // contiguous for j
        u16x4 ov;
#pragma unroll
        for (int j = 0; j < 4; ++j) ov[j] = f2bf(acc[mi][ni][j] + bvv);
        *(u16x4*)(Vt + ((size_t)(b * Dc + (c - 2 * Dc))) * Sc + sp) = ov;
      }
    }
  }
}

// split-K 256^2 GEMM: writes bf16 partials part[z][M][N]. grid=gx*gy*SPLIT.
template<int SPLIT>
__global__ __launch_bounds__(512) void gemm256_sk(
    const unsigned short* __restrict__ A, const unsigned short* __restrict__ Bt,
    unsigned short* __restrict__ part, int gx, int gy, int Ndim, int Ktot)
{
  __shared__ alignas(16) unsigned short As[2][256 * 64];
  __shared__ alignas(16) unsigned short Bs[2][256 * 64];
  const int t = threadIdx.x;
  const int lane = t & 63, w = t >> 6;
  const int wm = w >> 2, wn = w & 3;
  const int g = lane >> 4, li = lane & 15;
  const int nwg = gridDim.x, flat = blockIdx.x;
  const int swz = (flat & 7) * (nwg >> 3) + (flat >> 3);
  const int nTile = (swz % gx) * 256;
  const int mTile = ((swz / gx) % gy) * 256;
  const int z = swz / (gx * gy);
  const int Kseg = Ktot / SPLIT;

  f32x4 acc[8][4] = {};
  gemm256_core(A, Bt, As, Bs, acc, mTile, nTile, Ktot, z * Kseg, Kseg >> 6, t);

  unsigned short* po = part + (size_t)z * Mc * Ndim;
#pragma unroll
  for (int mi = 0; mi < 8; ++mi)
#pragma unroll
    for (int ni = 0; ni < 4; ++ni) {
      const int c = nTile + wn * 64 + ni * 16 + li;
#pragma unroll
      for (int j = 0; j < 4; ++j) {
        const int r = mTile + wm * 128 + mi * 16 + g * 4 + j;
        po[(size_t)r * Ndim + c] = f2bf(acc[mi][ni][j]);
      }
    }
}

// ---------------------------------------------------------------- attention
// QBLK=128, 512 blocks (XCD-swizzled), 4 waves split 2x2 over (q,k):
// wave (wq,wk) owns q rows [wq*64,+64) x k range [wk*1024,+1024).
// Each K/V LDS fragment feeds 4 MFMAs (2x the q-split version) -> per-wave
// LDS traffic halves; 16 barriers instead of 32. Softmax (no-max) is additive
// in k, so the two k-halves merge via one 32KB LDS reduction in the epilogue
// (overlaying the dead K buffers). LDS 80KB -> 2 blocks/CU.
__global__ __launch_bounds__(256, 2) void attn128(
    const unsigned short* __restrict__ QKV, const unsigned short* __restrict__ Vt,
    unsigned short* __restrict__ O)
{
  __shared__ alignas(16) char smem[80 * 1024];
  unsigned short* Qs  = (unsigned short*)smem;                 // 16 KB
  unsigned short* KsB = (unsigned short*)(smem + 16 * 1024);   // 32 KB: [dbuf*2+col]
  unsigned short* VsB = (unsigned short*)(smem + 48 * 1024);   // 32 KB

  const int t = threadIdx.x;
  const int lane = t & 63, w = t >> 6;
  const int wq = w >> 1, wk = w & 1;
  const int g = lane >> 4, li = lane & 15;
  const int flat = blockIdx.x;
  const int idx = ((flat & 7) << 6) | (flat >> 3);     // 512 blocks, 64/XCD
  const int qb = idx & 15, bh = idx >> 4;              // 16 q-blocks per head
  const int b = bh >> 4, h = bh & 15;

  const size_t qbase  = ((size_t)(b * Sc + qb * 128)) * QKVN + h * 64;
  const size_t kbase0 = ((size_t)b * Sc) * QKVN + Dc + h * 64;
  const size_t vbase0 = ((size_t)(b * Dc + h * 64)) * Sc;

#pragma unroll
  for (int i = 0; i < 4; ++i) {
    int idx2 = i * 256 + t, row = idx2 >> 3, sl = (idx2 & 7) ^ (row & 7);
    gload16(QKV + qbase + (size_t)row * QKVN + sl * 8, &Qs[idx2 * 8]);
  }
  const unsigned short* kg[2];
  const unsigned short* vg[2];
  int loff[2];
#pragma unroll
  for (int i = 0; i < 2; ++i) {
    int idx2 = i * 256 + t, row = idx2 >> 3, sl = (idx2 & 7) ^ (row & 7);
    kg[i] = QKV + kbase0 + (size_t)row * QKVN + sl * 8;
    vg[i] = Vt + vbase0 + (size_t)row * Sc + sl * 8;
    loff[i] = idx2 * 8;
  }
  const size_t KC = (size_t)1024 * QKVN;   // col-1 K offset (k += 1024)

  // prologue: stage chunk 0 of both k-columns into dbuf 0
#pragma unroll
  for (int c = 0; c < 2; ++c) {
    gload16(kg[0] + c * KC, &KsB[(0 * 2 + c) * 4096 + loff[0]]);
    gload16(kg[1] + c * KC, &KsB[(0 * 2 + c) * 4096 + loff[1]]);
    gload16(vg[0] + c * 1024, &VsB[(0 * 2 + c) * 4096 + loff[0]]);
    gload16(vg[1] + c * 1024, &VsB[(0 * 2 + c) * 4096 + loff[1]]);
  }
  kg[0] += 64 * QKVN; kg[1] += 64 * QKVN;
  vg[0] += 64;        vg[1] += 64;
  __syncthreads();   // Q + chunk0 (both cols) resident

  bf16x8 qf[4][2];
#pragma unroll
  for (int qi = 0; qi < 4; ++qi) {
    const int rq = wq * 64 + qi * 16 + li;
#pragma unroll
    for (int ks = 0; ks < 2; ++ks) {
      const int kb = ks * 64 + (g << 4);
      qf[qi][ks] = *(const bf16x8*)((const char*)Qs + rq * 128 + (kb ^ ((rq & 7) << 4)));
    }
  }
  bf16x8 ones;
#pragma unroll
  for (int e = 0; e < 8; ++e) ones[e] = (short)0x3F80;  // bf16 1.0

  f32x4 acc_o[4][4] = {};
  f32x4 acc_l[4] = {};

  for (int tt = 0; tt < 16; ++tt) {
    const int cur = tt & 1;
    if (tt + 1 < 16) {
      const int nb = cur ^ 1;
#pragma unroll
      for (int c = 0; c < 2; ++c) {
        gload16(kg[0] + c * KC, &KsB[(nb * 2 + c) * 4096 + loff[0]]);
        gload16(kg[1] + c * KC, &KsB[(nb * 2 + c) * 4096 + loff[1]]);
        gload16(vg[0] + c * 1024, &VsB[(nb * 2 + c) * 4096 + loff[0]]);
        gload16(vg[1] + c * 1024, &VsB[(nb * 2 + c) * 4096 + loff[1]]);
      }
      kg[0] += 64 * QKVN; kg[1] += 64 * QKVN;
      vg[0] += 64;        vg[1] += 64;
    }
    const char* Kc = (const char*)(KsB + (cur * 2 + wk) * 4096);
    const char* Vc = (const char*)(VsB + (cur * 2 + wk) * 4096);

    // swapped QK^T: each K fragment feeds all 4 q-subtiles
    f32x4 accs[4][4] = {};
#pragma unroll
    for (int ks = 0; ks < 2; ++ks) {
      const int kb = ks * 64 + (g << 4);
#pragma unroll
      for (int ni = 0; ni < 4; ++ni) {
        const int rk = ni * 16 + li;
        bf16x8 ak = *(const bf16x8*)(Kc + rk * 128 + (kb ^ ((rk & 7) << 4)));
#pragma unroll
        for (int qi = 0; qi < 4; ++qi)
          accs[qi][ni] = __builtin_amdgcn_mfma_f32_16x16x32_bf16(
              ak, qf[qi][ks], accs[qi][ni], 0, 0, 0);
      }
    }

    unsigned int pk[4][4][2];
#pragma unroll
    for (int qi = 0; qi < 4; ++qi)
#pragma unroll
      for (int ni = 0; ni < 4; ++ni) {
        float p0 = exp2f(accs[qi][ni][0]);
        float p1 = exp2f(accs[qi][ni][1]);
        float p2 = exp2f(accs[qi][ni][2]);
        float p3 = exp2f(accs[qi][ni][3]);
        pk[qi][ni][0] = cvt_pk_bf16(p0, p1);
        pk[qi][ni][1] = cvt_pk_bf16(p2, p3);
      }

#pragma unroll
    for (int ks = 0; ks < 2; ++ks) {
      bf16x8 ap[4];
#pragma unroll
      for (int qi = 0; qi < 4; ++qi) {
        u32x4 av = {pk[qi][2 * ks][0], pk[qi][2 * ks][1],
                    pk[qi][2 * ks + 1][0], pk[qi][2 * ks + 1][1]};
        ap[qi] = __builtin_bit_cast(bf16x8, av);
        acc_l[qi] = __builtin_amdgcn_mfma_f32_16x16x32_bf16(ap[qi], ones, acc_l[qi], 0, 0, 0);
      }
      const int kb = ks * 64 + (g << 4);
#pragma unroll
      for (int ni = 0; ni < 4; ++ni) {
        const int rd = ni * 16 + li;
        bf16x8 bv = *(const bf16x8*)(Vc + rd * 128 + (kb ^ ((rd & 7) << 4)));
#pragma unroll
        for (int qi = 0; qi < 4; ++qi)
          acc_o[qi][ni] = __builtin_amdgcn_mfma_f32_16x16x32_bf16(
              ap[qi], bv, acc_o[qi][ni], 0, 0, 0);
      }
    }

    __syncthreads();
  }

  // cross-wk reduction: wk=1 dumps partials into dead K/V LDS; wk=0 merges.
  float* red  = (float*)(smem + 16 * 1024);   // 32 KB: acc_o partials
  float* red2 = (float*)(smem + 48 * 1024);   // 512 B: acc_l partials
  if (wk == 1) {
#pragma unroll
    for (int qi = 0; qi < 4; ++qi) {
#pragma unroll
      for (int ni = 0; ni < 4; ++ni)
#pragma unroll
        for (int j = 0; j < 4; ++j)
          red[((((wq * 4 + qi) * 4 + ni) * 16) + g * 4 + j) * 16 + li] = acc_o[qi][ni][j];
      if (li == 0)
#pragma unroll
        for (int j = 0; j < 4; ++j)
          red2[(wq * 4 + qi) * 16 + g * 4 + j] = acc_l[qi][j];
    }
  }
  __syncthreads();
  if (wk == 0) {
    const size_t obase = ((size_t)(b * Sc + qb * 128)) * Dc + h * 64;
#pragma unroll
    for (int qi = 0; qi < 4; ++qi) {
      float denom[4];
#pragma unroll
      for (int j = 0; j < 4; ++j)
        denom[j] = 1.0f / (acc_l[qi][j] + red2[(wq * 4 + qi) * 16 + g * 4 + j]);
#pragma unroll
      for (int ni = 0; ni < 4; ++ni)
#pragma unroll
        for (int j = 0; j < 4; ++j) {
          float v = acc_o[qi][ni][j] +
                    red[((((wq * 4 + qi) * 4 + ni) * 16) + g * 4 + j) * 16 + li];
          int q = wq * 64 + qi * 16 + g * 4 + j;
          O[obase + (size_t)q * Dc + ni * 16 + li] = f2bf(v * denom[j]);
        }
    }
  }
}

// ------------------------- split-K (bf16) reduce + layernorm, bf16 residual
template<int SPLIT>
__global__ __launch_bounds__(256) void reduce_ln(
    const unsigned short* __restrict__ part, const float* __restrict__ bias,
    const unsigned short* __restrict__ resb, const float* __restrict__ g,
    const float* __restrict__ be, float* __restrict__ fout,
    unsigned short* __restrict__ xb_out)
{
  const int row = blockIdx.x, t = threadIdx.x;
  const size_t off = (size_t)row * Dc + t * 4;
  u16x4 rv = *(const u16x4*)(resb + off);
  f32x4 v;
#pragma unroll
  for (int j = 0; j < 4; ++j) v[j] = bf2f(rv[j]);
  v += *(const f32x4*)(bias + t * 4);
#pragma unroll
  for (int s = 0; s < SPLIT; ++s) {
    u16x4 pv = *(const u16x4*)(part + (size_t)s * Mc * Dc + off);
#pragma unroll
    for (int j = 0; j < 4; ++j) v[j] += bf2f(pv[j]);
  }

  float sm = v[0] + v[1] + v[2] + v[3];
  float q = v[0]*v[0] + v[1]*v[1] + v[2]*v[2] + v[3]*v[3];
#pragma unroll
  for (int o = 32; o; o >>= 1) {
    sm += __shfl_down(sm, o);
    q += __shfl_down(q, o);
  }
  __shared__ float rs_[4], rq_[4];
  const int lane = t & 63, w = t >> 6;
  if (lane == 0) { rs_[w] = sm; rq_[w] = q; }
  __syncthreads();
  sm = rs_[0] + rs_[1] + rs_[2] + rs_[3];
  q = rq_[0] + rq_[1] + rq_[2] + rq_[3];
  const float mu = sm * (1.0f / 1024.0f);
  const float var = q * (1.0f / 1024.0f) - mu * mu;
  const float rstd = rsqrtf(var + 1e-5f);
  f32x4 vg = *(const f32x4*)(g + t * 4);
  f32x4 vb = *(const f32x4*)(be + t * 4);
  f32x4 o; u16x4 ob;
#pragma unroll
  for (int j = 0; j < 4; ++j) {
    float val = (v[j] - mu) * rstd * vg[j] + vb[j];
    o[j] = val; ob[j] = f2bf(val);
  }
  if (fout) *(f32x4*)(fout + off) = o;
  *(u16x4*)(xb_out + off) = ob;
}

// ---------------------------------------------------------------- launch
extern "C" void kernel_launch(void* const* d_in, const int* in_sizes, int n_in,
                              void* d_out, int out_size, void* d_ws, size_t ws_size,
                              hipStream_t stream)
{
  (void)in_sizes; (void)n_in; (void)out_size; (void)ws_size;
  const int*   tokens = (const int*)d_in[0];
  const float* emb = (const float*)d_in[1];
  const float* Wq = (const float*)d_in[2];
  const float* bq = (const float*)d_in[3];
  const float* Wk = (const float*)d_in[4];
  const float* bk = (const float*)d_in[5];
  const float* Wv = (const float*)d_in[6];
  const float* bv = (const float*)d_in[7];
  const float* Wo = (const float*)d_in[8];
  const float* bo = (const float*)d_in[9];
  const float* W1 = (const float*)d_in[10];
  const float* b1 = (const float*)d_in[11];
  const float* W2 = (const float*)d_in[12];
  const float* b2 = (const float*)d_in[13];
  const float* g1 = (const float*)d_in[14];
  const float* be1 = (const float*)d_in[15];
  const float* g2 = (const float*)d_in[16];
  const float* be2 = (const float*)d_in[17];

  char* p = (char*)d_ws;
  auto take = [&](size_t bytes) { char* q = p; p += bytes; return q; };
  // ALL-layer transposed weights (prepped once, before the layer loop)
  unsigned short* Wqkvt = (unsigned short*)take((size_t)Lc * 3 * Dc * Dc * 2); // 36 MB
  unsigned short* Wot = (unsigned short*)take((size_t)Lc * Dc * Dc * 2);       // 12 MB
  unsigned short* W1t = (unsigned short*)take((size_t)Lc * Dc * Fc * 2);       // 48 MB
  unsigned short* W2t = (unsigned short*)take((size_t)Lc * Fc * Dc * 2);       // 48 MB
  float*          bqkv = (float*)take((size_t)Lc * QKVN * 4);
  unsigned short* xb  = (unsigned short*)take((size_t)Mc * Dc * 2);
  unsigned short* QKVb = (unsigned short*)take((size_t)Mc * QKVN * 2);
  unsigned short* Vtb = (unsigned short*)take((size_t)Bc * Dc * Sc * 2);
  unsigned short* Ob  = (unsigned short*)take((size_t)Mc * Dc * 2);
  unsigned short* ff1 = (unsigned short*)take((size_t)Mc * Fc * 2);
  // split-K bf16 partials (4 x 8 MB) overlay QKVb+Vtb (dead after attn)
  unsigned short* part = QKVb;

  dim3 blk(256);
  prep_weights<<<dim3(Lc * 780), blk, 0, stream>>>(
      Wq, Wk, Wv, Wo, W1, W2, bq, bk, bv, Wqkvt, Wot, W1t, W2t, bqkv);
  embed_kernel<<<dim3(Mc), blk, 0, stream>>>(tokens, emb, xb);

  for (int l = 0; l < Lc; ++l) {
    const int ob = l * Dc;
    const unsigned short* Wqkvt_l = Wqkvt + (size_t)l * 3 * Dc * Dc;
    const unsigned short* Wot_l = Wot + (size_t)l * Dc * Dc;
    const unsigned short* W1t_l = W1t + (size_t)l * Dc * Fc;
    const unsigned short* W2t_l = W2t + (size_t)l * Fc * Dc;

    // fused QKV projection: [4096 x 3072]; V cols written direct to Vtb
    gemm256<<<dim3((Mc / 256) * (QKVN / 256)), dim3(512), 0, stream>>>(
        xb, Wqkvt_l, bqkv + l * QKVN, QKVb, Vtb, QKVN / 256, QKVN, Dc, 0);
    attn128<<<dim3(512), blk, 0, stream>>>(QKVb, Vtb, Ob);

    // attention out-proj: 8-phase split-K=4 bf16 partials, fused reduce+LN1
    gemm256_sk<4><<<dim3((Dc / 256) * (Mc / 256) * 4), dim3(512), 0, stream>>>(
        Ob, Wot_l, part, Dc / 256, Mc / 256, Dc, Dc);
    reduce_ln<4><<<dim3(Mc), blk, 0, stream>>>(
        part, bo + ob, xb, g1 + ob, be1 + ob, nullptr, xb);

    // FF1: [4096 x 4096]
    gemm256<<<dim3((Mc / 256) * (Fc / 256)), dim3(512), 0, stream>>>(
        xb, W1t_l, b1 + l * Fc, ff1, nullptr, Fc / 256, Fc, Dc, 1);

    // FF2: 8-phase split-K=4 bf16 partials, fused reduce+LN2
    gemm256_sk<4><<<dim3((Dc / 256) * (Mc / 256) * 4), dim3(512), 0, stream>>>(
        ff1, W2t_l, part, Dc / 256, Mc / 256, Dc, Fc);
    reduce_ln<4><<<dim3(Mc), blk, 0, stream>>>(
        part, b2 + ob, xb, g2 + ob, be2 + ob,
        (l == Lc - 1) ? (float*)d_out : nullptr, xb);
  }
}